// Round 12
// baseline (351.892 us; speedup 1.0000x reference)
//
#include <hip/hip_runtime.h>
#include <math.h>

#define NPTS 32768
#define NB 32
#define PP 1024
#define KK 20

using bf16x8 = __attribute__((ext_vector_type(8))) short;
using f32x4 = __attribute__((ext_vector_type(4))) float;

// ---------------- workspace layout ----------------
constexpr size_t OFF_X1 = 0;                                  // x1hl [N,128] bf16 (hi 0..63, lo 64..127)
constexpr size_t OFF_IDX = OFF_X1 + (size_t)NPTS * 64 * 4;    // [N,20] i32
constexpr size_t OFF_U = OFF_IDX + (size_t)NPTS * KK * 4;     // u2 [N,128] f32
constexpr size_t OFF_V = OFF_U + (size_t)NPTS * 128 * 4;      // v2 [N,128] f32
constexpr size_t OFF_X2 = OFF_V + (size_t)NPTS * 128 * 4;     // x2hl [N,256] bf16
constexpr size_t OFF_H = OFF_X2 + (size_t)NPTS * 128 * 4;     // h [N,128] f32
constexpr size_t OFF_PART = OFF_H + (size_t)NPTS * 128 * 4;   // 32*8*128 f32
constexpr size_t OFF_SQN = OFF_PART + (size_t)32 * 8 * 128 * 4;  // [N] f32
// pk (both kNNs) @ OFF_U: N*8*20 u32 = 21 MB, spans U + start of V.
//  knn1 pk dead before precompute1 writes u1/v1.
//  knn2 pk written after edge_conv1 consumed u1/v1, dead before pre2_mfma.

// ---------------- register top-K: v_med3_u32 insert ----------------
__device__ __forceinline__ void topk_insert(unsigned (&l)[KK], unsigned key) {
#pragma unroll
  for (int j = KK - 1; j >= 1; --j) {
    unsigned r;
    asm("v_med3_u32 %0, %1, %2, %3" : "=v"(r) : "v"(key), "v"(l[j - 1]), "v"(l[j]));
    l[j] = r;
  }
  l[0] = key < l[0] ? key : l[0];
}

__device__ __forceinline__ unsigned pack_key(float dist, int q) {
  return (__float_as_uint(dist) & 0xFFFFFC00u) | (unsigned)q;
}

// hi/lo bf16 split: |x - (hi+lo)| <= 2^-16 |x|
__device__ __forceinline__ void split_bf16(float x, short& hi, short& lo) {
  unsigned u = __float_as_uint(x);
  hi = (short)(u >> 16);
  float fh = __uint_as_float(u & 0xFFFF0000u);
  float r = x - fh;
  lo = (short)(__float_as_uint(r) >> 16);
}

// ---------------- kNN1 (D=3): LDS SoA, dual lists merged in-kernel ----------------
template <int S>
__global__ __launch_bounds__(256, 4) void knn_topk3(const float* __restrict__ x,
                                                    unsigned* __restrict__ pk) {
  constexpr int CH = PP / S;
  __shared__ __align__(16) float xs[1024];
  __shared__ __align__(16) float ys[1024];
  __shared__ __align__(16) float zs[1024];
  int bx = blockIdx.x;
  int s = bx % S;
  int tile = (bx / S) % (PP / 256);
  int b = bx / (S * (PP / 256));
  int tid = threadIdx.x;
  const float* xb = x + (size_t)b * PP * 3;

  for (int t = tid; t < 768; t += 256) {
    float4 v = ((const float4*)xb)[t];
    int e = 4 * t;
    float vals[4] = {v.x, v.y, v.z, v.w};
#pragma unroll
    for (int j = 0; j < 4; ++j) {
      int p = (e + j) / 3, d = (e + j) % 3;
      if (d == 0) xs[p] = vals[j];
      else if (d == 1) ys[p] = vals[j];
      else zs[p] = vals[j];
    }
  }
  __syncthreads();

  int i = tile * 256 + tid;
  float xi0 = xs[i], xi1 = ys[i], xi2 = zs[i];

  unsigned la[KK], lb_[KK];
#pragma unroll
  for (int j = 0; j < KK; ++j) { la[j] = 0xFFFFFFFFu; lb_[j] = 0xFFFFFFFFu; }

  int q0 = s * CH;
  float4 qx = *(const float4*)&xs[q0];
  float4 qy = *(const float4*)&ys[q0];
  float4 qz = *(const float4*)&zs[q0];
  for (int c = 0; c < CH; c += 4) {
    int qm = (q0 + c + 4) & 1023;  // masked: last prefetch unused
    float4 nqx = *(const float4*)&xs[qm];
    float4 nqy = *(const float4*)&ys[qm];
    float4 nqz = *(const float4*)&zs[qm];
    float cx[4] = {qx.x, qx.y, qx.z, qx.w};
    float cy[4] = {qy.x, qy.y, qy.z, qy.w};
    float cz[4] = {qz.x, qz.y, qz.z, qz.w};
    // dual lists: j=0,1 -> la ; j=2,3 -> lb_ (independent chains, 2x ILP)
    {
      float d0 = xi0 - cx[0], d1 = xi1 - cy[0], d2 = xi2 - cz[0];
      float e0 = xi0 - cx[2], e1 = xi1 - cy[2], e2 = xi2 - cz[2];
      topk_insert(la, pack_key(fmaf(d0, d0, fmaf(d1, d1, d2 * d2)), q0 + c + 0));
      topk_insert(lb_, pack_key(fmaf(e0, e0, fmaf(e1, e1, e2 * e2)), q0 + c + 2));
    }
    {
      float d0 = xi0 - cx[1], d1 = xi1 - cy[1], d2 = xi2 - cz[1];
      float e0 = xi0 - cx[3], e1 = xi1 - cy[3], e2 = xi2 - cz[3];
      topk_insert(la, pack_key(fmaf(d0, d0, fmaf(d1, d1, d2 * d2)), q0 + c + 1));
      topk_insert(lb_, pack_key(fmaf(e0, e0, fmaf(e1, e1, e2 * e2)), q0 + c + 3));
    }
    qx = nqx; qy = nqy; qz = nqz;
  }
  // merge lb_ -> la (both sorted ascending, keys unique): exact
  for (int j = 0; j < KK; ++j) {
    unsigned key = lb_[j];
    if (key >= la[KK - 1]) break;
    topk_insert(la, key);
  }
  size_t base = ((size_t)b * PP + i) * S + s;
#pragma unroll
  for (int j = 0; j < KK; ++j) pk[base * KK + j] = la[j];
}

// merge S sorted sublists; early break exact (keys unique, ascending)
template <int S>
__global__ __launch_bounds__(256) void knn_merge(const unsigned* __restrict__ pk,
                                                 int* __restrict__ idx_out) {
  int p = blockIdx.x * 256 + threadIdx.x;
  const unsigned* g = pk + (size_t)p * S * KK;
  unsigned l[KK];
#pragma unroll
  for (int j = 0; j < KK; ++j) l[j] = g[j];
  for (int s = 1; s < S; ++s) {
    const unsigned* gs = g + s * KK;
    for (int j = 0; j < KK; ++j) {
      unsigned key = gs[j];
      if (key >= l[KK - 1]) break;  // sorted: rest cannot qualify
      topk_insert(l, key);
    }
  }
#pragma unroll
  for (int j = 0; j < KK; ++j) idx_out[(size_t)p * KK + j] = (int)(l[j] & 1023u);
}

// ---------------- EdgeConv1 precompute ----------------
__global__ __launch_bounds__(256) void precompute1(const float* __restrict__ pos,
                                                   const float* __restrict__ W1,
                                                   const float* __restrict__ b1,
                                                   float* __restrict__ u1,
                                                   float* __restrict__ v1) {
  int gid = blockIdx.x * 256 + threadIdx.x;  // over N*64
  int i = gid >> 6, c = gid & 63;
  float p0 = pos[(size_t)i * 3 + 0], p1 = pos[(size_t)i * 3 + 1], p2 = pos[(size_t)i * 3 + 2];
  float a0 = W1[0 * 64 + c], a1 = W1[1 * 64 + c], a2 = W1[2 * 64 + c];
  float g0 = W1[3 * 64 + c], g1 = W1[4 * 64 + c], g2 = W1[5 * 64 + c];
  float v = fmaf(p0, g0, fmaf(p1, g1, p2 * g2));
  float u = b1[c];
  u = fmaf(p0, a0 - g0, u);
  u = fmaf(p1, a1 - g1, u);
  u = fmaf(p2, a2 - g2, u);
  u1[gid] = u;
  v1[gid] = v;
}

// ---------------- EdgeConv1 via MFMA: k-quartered, max in registers ----------------
// Block = 16 points, 4 waves each own 5 neighbors; per-wave register max;
// partials merged via one 4-way LDS max (exactly associative).
__global__ __launch_bounds__(256) void edge_conv1_mfma(
    const float* __restrict__ u1, const float* __restrict__ v1,
    const int* __restrict__ idx, const float* __restrict__ W2,
    const float* __restrict__ scale, const float* __restrict__ bias,
    const float* __restrict__ b2,
    short* __restrict__ x1hl, float* __restrict__ sqn) {
  __shared__ int jt[16 * KK];
  __shared__ float mxs[4][16 * 68];
  int tid = threadIdx.x;
  int p0 = blockIdx.x * 16;  // 16 | 1024: no cloud straddle
  int b = p0 >> 10;
  for (int t = tid; t < 16 * KK; t += 256)
    jt[t] = (b << 10) + idx[(size_t)(p0 + t / KK) * KK + t % KK];
  int w = tid >> 6, l = tid & 63, quad = l >> 4, lm = l & 15;
  int kq = quad * 8;
  // B fragments: B[k][n], lane holds n = lm, k = ks*32 + kq + jj
  bf16x8 Bh[4][2], Bl[4][2];
#pragma unroll
  for (int nt = 0; nt < 4; ++nt) {
#pragma unroll
    for (int ks = 0; ks < 2; ++ks) {
#pragma unroll
      for (int jj = 0; jj < 8; ++jj) {
        float wv = W2[(size_t)(ks * 32 + kq + jj) * 64 + nt * 16 + lm];
        short hi, lo;
        split_bf16(wv, hi, lo);
        Bh[nt][ks][jj] = hi;
        Bl[nt][ks][jj] = lo;
      }
    }
  }
  // per-lane point (A-row m = lm): u' = u*scale + bias folded once
  const float* urow = u1 + (size_t)(p0 + lm) * 64;
  float up[2][8], sc[2][8];
#pragma unroll
  for (int ks = 0; ks < 2; ++ks) {
    int koff = ks * 32 + kq;
    float4 ua = *(const float4*)(urow + koff);
    float4 ub = *(const float4*)(urow + koff + 4);
    float4 sa = *(const float4*)(scale + koff);
    float4 sb = *(const float4*)(scale + koff + 4);
    float4 ca = *(const float4*)(bias + koff);
    float4 cb4 = *(const float4*)(bias + koff + 4);
    sc[ks][0] = sa.x; sc[ks][1] = sa.y; sc[ks][2] = sa.z; sc[ks][3] = sa.w;
    sc[ks][4] = sb.x; sc[ks][5] = sb.y; sc[ks][6] = sb.z; sc[ks][7] = sb.w;
    up[ks][0] = fmaf(ua.x, sa.x, ca.x);
    up[ks][1] = fmaf(ua.y, sa.y, ca.y);
    up[ks][2] = fmaf(ua.z, sa.z, ca.z);
    up[ks][3] = fmaf(ua.w, sa.w, ca.w);
    up[ks][4] = fmaf(ub.x, sb.x, cb4.x);
    up[ks][5] = fmaf(ub.y, sb.y, cb4.y);
    up[ks][6] = fmaf(ub.z, sb.z, cb4.z);
    up[ks][7] = fmaf(ub.w, sb.w, cb4.w);
  }
  __syncthreads();

  f32x4 mx[4];
#pragma unroll
  for (int nt = 0; nt < 4; ++nt)
    mx[nt] = (f32x4){-__builtin_inff(), -__builtin_inff(), -__builtin_inff(), -__builtin_inff()};

  for (int k = w * 5; k < w * 5 + 5; ++k) {
    int j = jt[lm * KK + k];
    const float* vrow = v1 + (size_t)j * 64;
    f32x4 acc[4];
#pragma unroll
    for (int nt = 0; nt < 4; ++nt) acc[nt] = (f32x4){0.f, 0.f, 0.f, 0.f};
#pragma unroll
    for (int ks = 0; ks < 2; ++ks) {
      int koff = ks * 32 + kq;
      float4 va = *(const float4*)(vrow + koff);
      float4 vb = *(const float4*)(vrow + koff + 4);
      float hv[8];
      hv[0] = fmaxf(fmaf(va.x, sc[ks][0], up[ks][0]), 0.f);
      hv[1] = fmaxf(fmaf(va.y, sc[ks][1], up[ks][1]), 0.f);
      hv[2] = fmaxf(fmaf(va.z, sc[ks][2], up[ks][2]), 0.f);
      hv[3] = fmaxf(fmaf(va.w, sc[ks][3], up[ks][3]), 0.f);
      hv[4] = fmaxf(fmaf(vb.x, sc[ks][4], up[ks][4]), 0.f);
      hv[5] = fmaxf(fmaf(vb.y, sc[ks][5], up[ks][5]), 0.f);
      hv[6] = fmaxf(fmaf(vb.z, sc[ks][6], up[ks][6]), 0.f);
      hv[7] = fmaxf(fmaf(vb.w, sc[ks][7], up[ks][7]), 0.f);
      bf16x8 Ah, Al;
#pragma unroll
      for (int jj = 0; jj < 8; ++jj) {
        short hi, lo;
        split_bf16(hv[jj], hi, lo);
        Ah[jj] = hi;
        Al[jj] = lo;
      }
#pragma unroll
      for (int nt = 0; nt < 4; ++nt) {
        acc[nt] = __builtin_amdgcn_mfma_f32_16x16x32_bf16(Ah, Bh[nt][ks], acc[nt], 0, 0, 0);
        acc[nt] = __builtin_amdgcn_mfma_f32_16x16x32_bf16(Al, Bh[nt][ks], acc[nt], 0, 0, 0);
        acc[nt] = __builtin_amdgcn_mfma_f32_16x16x32_bf16(Ah, Bl[nt][ks], acc[nt], 0, 0, 0);
      }
    }
#pragma unroll
    for (int nt = 0; nt < 4; ++nt) {
#pragma unroll
      for (int r = 0; r < 4; ++r) mx[nt][r] = fmaxf(mx[nt][r], acc[nt][r]);
    }
  }
  // per-wave partial: C row = quad*4 + r, col = nt*16 + lm (no race across w)
#pragma unroll
  for (int nt = 0; nt < 4; ++nt)
#pragma unroll
    for (int r = 0; r < 4; ++r)
      mxs[w][(quad * 4 + r) * 68 + nt * 16 + lm] = mx[nt][r];
  __syncthreads();
  // 4-way max reduce + epilogue: 1024 outputs, 4 per thread
  for (int o = tid; o < 1024; o += 256) {
    int p = o >> 6, c = o & 63;
    float m = fmaxf(fmaxf(mxs[0][p * 68 + c], mxs[1][p * 68 + c]),
                    fmaxf(mxs[2][p * 68 + c], mxs[3][p * 68 + c])) + b2[c];
    short hi, lo;
    split_bf16(m, hi, lo);
    size_t gi = (size_t)(p0 + p) * 128 + c;
    x1hl[gi] = hi;
    x1hl[gi + 64] = lo;
    mxs[0][p * 68 + c] = m;
  }
  __syncthreads();
  if (tid < 16) {
    float ss = 0.f;
    for (int c = 0; c < 64; ++c) {
      float v = mxs[0][tid * 68 + c];
      ss = fmaf(v, v, ss);
    }
    sqn[p0 + tid] = ss;
  }
}

// ---------------- kNN2 via MFMA: double-buffered LDS tiles + dual lists ----------------
__global__ __launch_bounds__(256, 4) void knn2_mfma(const short* __restrict__ x1hl,
                                                    const float* __restrict__ sqn,
                                                    unsigned* __restrict__ pk) {
  constexpr int TS = 72;  // LDS row stride (shorts): b128-aligned, padded
  __shared__ float sqs[512];
  __shared__ __align__(16) short tileH[2][64 * TS];
  __shared__ __align__(16) short tileL[2][64 * TS];
  int bx = blockIdx.x;
  int s = bx & 1;
  int pb = bx >> 1;
  int p0 = pb * 64;
  int b = p0 >> 10;
  int tid = threadIdx.x;
  for (int t = tid; t < 512; t += 256) sqs[t] = sqn[(size_t)b * PP + s * 512 + t];
  int w = tid >> 6, l = tid & 63, quad = l >> 4, lm = l & 15;
  size_t gi = (size_t)p0 + w * 16 + lm;
  const short* brow = x1hl + gi * 128 + quad * 8;
  bf16x8 Bh0 = *(const bf16x8*)(brow);
  bf16x8 Bl0 = *(const bf16x8*)(brow + 64);
  bf16x8 Bh1 = *(const bf16x8*)(brow + 32);
  bf16x8 Bl1 = *(const bf16x8*)(brow + 96);
  float sqi = sqn[gi];

  unsigned la[KK], lc[KK];
#pragma unroll
  for (int j = 0; j < KK; ++j) { la[j] = 0xFFFFFFFFu; lc[j] = 0xFFFFFFFFu; }

  int rr = tid & 63, seg = tid >> 6;
  const short* srcbase = x1hl + ((size_t)b * PP + s * 512 + rr) * 128 + seg * 32;
  {
    bf16x8 r0 = *(const bf16x8*)(srcbase);
    bf16x8 r1 = *(const bf16x8*)(srcbase + 8);
    bf16x8 r2 = *(const bf16x8*)(srcbase + 16);
    bf16x8 r3 = *(const bf16x8*)(srcbase + 24);
    short* dst = ((seg < 2) ? tileH[0] : tileL[0]) + rr * TS + (seg & 1) * 32;
    *(bf16x8*)(dst) = r0;
    *(bf16x8*)(dst + 8) = r1;
    *(bf16x8*)(dst + 16) = r2;
    *(bf16x8*)(dst + 24) = r3;
  }
  __syncthreads();

  for (int tile = 0; tile < 8; ++tile) {
    int buf = tile & 1;
    bf16x8 r0, r1, r2, r3;
    if (tile < 7) {
      const short* src = srcbase + (size_t)(tile + 1) * 64 * 128;
      r0 = *(const bf16x8*)(src);
      r1 = *(const bf16x8*)(src + 8);
      r2 = *(const bf16x8*)(src + 16);
      r3 = *(const bf16x8*)(src + 24);
    }
#pragma unroll
    for (int it = 0; it < 4; ++it) {
      int row = it * 16 + lm;
      const short* aH = tileH[buf] + row * TS + quad * 8;
      const short* aL = tileL[buf] + row * TS + quad * 8;
      bf16x8 Ah0 = *(const bf16x8*)(aH);
      bf16x8 Ah1 = *(const bf16x8*)(aH + 32);
      bf16x8 Al0 = *(const bf16x8*)(aL);
      bf16x8 Al1 = *(const bf16x8*)(aL + 32);

      f32x4 acc = (f32x4){0.f, 0.f, 0.f, 0.f};
      acc = __builtin_amdgcn_mfma_f32_16x16x32_bf16(Ah0, Bh0, acc, 0, 0, 0);
      acc = __builtin_amdgcn_mfma_f32_16x16x32_bf16(Al0, Bh0, acc, 0, 0, 0);
      acc = __builtin_amdgcn_mfma_f32_16x16x32_bf16(Ah0, Bl0, acc, 0, 0, 0);
      acc = __builtin_amdgcn_mfma_f32_16x16x32_bf16(Ah1, Bh1, acc, 0, 0, 0);
      acc = __builtin_amdgcn_mfma_f32_16x16x32_bf16(Al1, Bh1, acc, 0, 0, 0);
      acc = __builtin_amdgcn_mfma_f32_16x16x32_bf16(Ah1, Bl1, acc, 0, 0, 0);

      int qloc = tile * 64 + it * 16 + quad * 4;
      int qg = s * 512 + qloc;
      float d0 = fmaxf(0.f, fmaf(-2.f, acc[0], sqi + sqs[qloc + 0]));
      float d2 = fmaxf(0.f, fmaf(-2.f, acc[2], sqi + sqs[qloc + 2]));
      topk_insert(la, pack_key(d0, qg + 0));
      topk_insert(lc, pack_key(d2, qg + 2));
      float d1 = fmaxf(0.f, fmaf(-2.f, acc[1], sqi + sqs[qloc + 1]));
      float d3 = fmaxf(0.f, fmaf(-2.f, acc[3], sqi + sqs[qloc + 3]));
      topk_insert(la, pack_key(d1, qg + 1));
      topk_insert(lc, pack_key(d3, qg + 3));
    }
    if (tile < 7) {
      __syncthreads();
      short* dst = ((seg < 2) ? tileH[buf ^ 1] : tileL[buf ^ 1]) + rr * TS + (seg & 1) * 32;
      *(bf16x8*)(dst) = r0;
      *(bf16x8*)(dst + 8) = r1;
      *(bf16x8*)(dst + 16) = r2;
      *(bf16x8*)(dst + 24) = r3;
      __syncthreads();
    }
  }
  for (int j = 0; j < KK; ++j) {
    unsigned key = lc[j];
    if (key >= la[KK - 1]) break;
    topk_insert(la, key);
  }
  unsigned sub = (unsigned)(s * 4 + quad);
  unsigned* dst = pk + ((size_t)gi * 8 + sub) * KK;
#pragma unroll
  for (int j = 0; j < KK; ++j) dst[j] = la[j];
}

// ---------------- EdgeConv2 precompute via MFMA ----------------
__global__ __launch_bounds__(256) void pre2_mfma(const short* __restrict__ x1hl,
                                                 const float* __restrict__ cW,
                                                 const float* __restrict__ cb,
                                                 float* __restrict__ u2,
                                                 float* __restrict__ v2) {
  constexpr int BS = 72;
  __shared__ short Bh[128 * BS];
  __shared__ short Bl[128 * BS];
  int tid = threadIdx.x;
  int nh = blockIdx.x & 1;
  int p0 = (blockIdx.x >> 1) * 64;
  for (int t = tid; t < 64 * 128; t += 256) {
    int k = t >> 7, n = t & 127;
    float wb_ = cW[(size_t)(64 + k) * 128 + n];
    float wv = nh ? wb_ : (cW[(size_t)k * 128 + n] - wb_);
    short hi, lo;
    split_bf16(wv, hi, lo);
    Bh[n * BS + k] = hi;
    Bl[n * BS + k] = lo;
  }
  __syncthreads();
  int w = tid >> 6, l = tid & 63, quad = l >> 4, lm = l & 15;
  int row = p0 + w * 16 + lm;
  f32x4 acc[8];
#pragma unroll
  for (int nt = 0; nt < 8; ++nt) acc[nt] = (f32x4){0.f, 0.f, 0.f, 0.f};
#pragma unroll
  for (int ks = 0; ks < 2; ++ks) {
    int kb = ks * 32 + quad * 8;
    bf16x8 Ah = *(const bf16x8*)(x1hl + (size_t)row * 128 + kb);
    bf16x8 Al = *(const bf16x8*)(x1hl + (size_t)row * 128 + 64 + kb);
#pragma unroll
    for (int nt = 0; nt < 8; ++nt) {
      bf16x8 Wh = *(const bf16x8*)(Bh + (nt * 16 + lm) * BS + kb);
      bf16x8 Wl = *(const bf16x8*)(Bl + (nt * 16 + lm) * BS + kb);
      acc[nt] = __builtin_amdgcn_mfma_f32_16x16x32_bf16(Ah, Wh, acc[nt], 0, 0, 0);
      acc[nt] = __builtin_amdgcn_mfma_f32_16x16x32_bf16(Al, Wh, acc[nt], 0, 0, 0);
      acc[nt] = __builtin_amdgcn_mfma_f32_16x16x32_bf16(Ah, Wl, acc[nt], 0, 0, 0);
    }
  }
  float* out = nh ? v2 : u2;
  int prow = p0 + w * 16 + quad * 4;
#pragma unroll
  for (int nt = 0; nt < 8; ++nt) {
    int col = nt * 16 + lm;
    float bias = nh ? 0.f : cb[col];
#pragma unroll
    for (int r = 0; r < 4; ++r)
      out[(size_t)(prow + r) * 128 + col] = acc[nt][r] + bias;
  }
}

__global__ __launch_bounds__(256) void gathermax2(const float* __restrict__ u2,
                                                  const float* __restrict__ v2,
                                                  const int* __restrict__ idx,
                                                  short* __restrict__ x2hl) {
  int gid = blockIdx.x * 256 + threadIdx.x;  // over N*128
  int i = gid >> 7, c = gid & 127;
  int b = i >> 10;
  const int* myidx = idx + (size_t)i * KK;
  float m = -__builtin_inff();
  for (int k = 0; k < KK; ++k) {
    int j = (b << 10) + myidx[k];
    m = fmaxf(m, v2[(size_t)j * 128 + c]);
  }
  float x = u2[gid] + m;
  short hi, lo;
  split_bf16(x, hi, lo);
  x2hl[(size_t)i * 256 + c] = hi;
  x2hl[(size_t)i * 256 + 128 + c] = lo;
}

// ---------------- final linear via MFMA ----------------
__global__ __launch_bounds__(256) void lin_mfma(const short* __restrict__ x1hl,
                                                const short* __restrict__ x2hl,
                                                const float* __restrict__ LW,
                                                const float* __restrict__ lb,
                                                float* __restrict__ h) {
  constexpr int BS = 200;
  __shared__ short Bh[64 * BS];
  __shared__ short Bl[64 * BS];
  int tid = threadIdx.x;
  int nh = blockIdx.x & 1;
  int p0 = (blockIdx.x >> 1) * 64;
  for (int t = tid; t < 192 * 64; t += 256) {
    int k = t >> 6, n = t & 63;
    float wv = LW[(size_t)k * 128 + nh * 64 + n];
    short hi, lo;
    split_bf16(wv, hi, lo);
    Bh[n * BS + k] = hi;
    Bl[n * BS + k] = lo;
  }
  __syncthreads();
  int w = tid >> 6, l = tid & 63, quad = l >> 4, lm = l & 15;
  int row = p0 + w * 16 + lm;
  f32x4 acc[4];
#pragma unroll
  for (int nt = 0; nt < 4; ++nt) acc[nt] = (f32x4){0.f, 0.f, 0.f, 0.f};
#pragma unroll
  for (int ks = 0; ks < 6; ++ks) {
    int kb = ks * 32 + quad * 8;
    bf16x8 Ah, Al;
    if (ks < 2) {
      Ah = *(const bf16x8*)(x1hl + (size_t)row * 128 + kb);
      Al = *(const bf16x8*)(x1hl + (size_t)row * 128 + 64 + kb);
    } else {
      Ah = *(const bf16x8*)(x2hl + (size_t)row * 256 + (kb - 64));
      Al = *(const bf16x8*)(x2hl + (size_t)row * 256 + 128 + (kb - 64));
    }
#pragma unroll
    for (int nt = 0; nt < 4; ++nt) {
      bf16x8 Wh = *(const bf16x8*)(Bh + (nt * 16 + lm) * BS + kb);
      bf16x8 Wl = *(const bf16x8*)(Bl + (nt * 16 + lm) * BS + kb);
      acc[nt] = __builtin_amdgcn_mfma_f32_16x16x32_bf16(Ah, Wh, acc[nt], 0, 0, 0);
      acc[nt] = __builtin_amdgcn_mfma_f32_16x16x32_bf16(Al, Wh, acc[nt], 0, 0, 0);
      acc[nt] = __builtin_amdgcn_mfma_f32_16x16x32_bf16(Ah, Wl, acc[nt], 0, 0, 0);
    }
  }
  int prow = p0 + w * 16 + quad * 4;
#pragma unroll
  for (int nt = 0; nt < 4; ++nt) {
    int col = nh * 64 + nt * 16 + lm;
    float bias = lb[col];
#pragma unroll
    for (int r = 0; r < 4; ++r)
      h[(size_t)(prow + r) * 128 + col] = acc[nt][r] + bias;
  }
}

// ---------------- segment max ----------------
__global__ __launch_bounds__(128) void segmax_a(const float* __restrict__ h,
                                                float* __restrict__ part) {
  int b = blockIdx.x >> 3, chunk = blockIdx.x & 7;
  int c = threadIdx.x;
  float m = -__builtin_inff();
  for (int p = 0; p < 128; ++p) {
    size_t i = (size_t)b * PP + chunk * 128 + p;
    m = fmaxf(m, h[i * 128 + c]);
  }
  part[(size_t)blockIdx.x * 128 + c] = m;
}

__global__ __launch_bounds__(128) void segmax_b(const float* __restrict__ part,
                                                float* __restrict__ out) {
  int b = blockIdx.x;
  int c = threadIdx.x;
  float m = -__builtin_inff();
  for (int k = 0; k < 8; ++k) m = fmaxf(m, part[((size_t)b * 8 + k) * 128 + c]);
  out[(size_t)b * 128 + c] = m;
}

// ---------------- launch ----------------
extern "C" void kernel_launch(void* const* d_in, const int* in_sizes, int n_in,
                              void* d_out, int out_size, void* d_ws, size_t ws_size,
                              hipStream_t stream) {
  const float* pos = (const float*)d_in[0];
  const float* W1 = (const float*)d_in[2];
  const float* b1 = (const float*)d_in[3];
  const float* bn_s = (const float*)d_in[4];
  const float* bn_b = (const float*)d_in[5];
  const float* W2 = (const float*)d_in[6];
  const float* b2 = (const float*)d_in[7];
  const float* cW = (const float*)d_in[8];
  const float* cb = (const float*)d_in[9];
  const float* LW = (const float*)d_in[10];
  const float* lb = (const float*)d_in[11];
  float* out = (float*)d_out;

  char* ws = (char*)d_ws;
  short* x1hl = (short*)(ws + OFF_X1);
  int* idx = (int*)(ws + OFF_IDX);
  float* u1 = (float*)(ws + OFF_U);
  float* v1 = (float*)(ws + OFF_V);
  float* u2 = (float*)(ws + OFF_U);
  float* v2 = (float*)(ws + OFF_V);
  short* x2hl = (short*)(ws + OFF_X2);
  float* hbuf = (float*)(ws + OFF_H);
  float* part = (float*)(ws + OFF_PART);
  float* sqn = (float*)(ws + OFF_SQN);
  unsigned* pk = (unsigned*)(ws + OFF_U);  // see lifetime notes above

  // 1. kNN on pos (8-way split, dual lists merged in-kernel -> 8 sublists)
  knn_topk3<8><<<NB * 4 * 8, 256, 0, stream>>>(pos, pk);
  knn_merge<8><<<NPTS / 256, 256, 0, stream>>>(pk, idx);
  // 2. u1/v1
  precompute1<<<NPTS * 64 / 256, 256, 0, stream>>>(pos, W1, b1, u1, v1);
  // 3. EdgeConv1 (MFMA, k-quartered reg-max) -> x1hl + sqn
  edge_conv1_mfma<<<NPTS / 16, 256, 0, stream>>>(u1, v1, idx, W2, bn_s, bn_b, b2,
                                                 x1hl, sqn);
  // 4. kNN on x1 (MFMA + double-buffered LDS tiles, in-kernel dual-list merge)
  knn2_mfma<<<NPTS / 64 * 2, 256, 0, stream>>>(x1hl, sqn, pk);
  knn_merge<8><<<NPTS / 256, 256, 0, stream>>>(pk, idx);
  // 5. u2/v2 (MFMA)
  pre2_mfma<<<NPTS / 64 * 2, 256, 0, stream>>>(x1hl, cW, cb, u2, v2);
  // 6. gather + max -> x2hl
  gathermax2<<<NPTS * 128 / 256, 256, 0, stream>>>(u2, v2, idx, x2hl);
  // 7. final linear (MFMA) -> h
  lin_mfma<<<NPTS / 64 * 2, 256, 0, stream>>>(x1hl, x2hl, LW, lb, hbuf);
  // 8. segment max -> out
  segmax_a<<<NB * 8, 128, 0, stream>>>(hbuf, part);
  segmax_b<<<NB, 128, 0, stream>>>(part, out);
}

// Round 13
// 315.250 us; speedup vs baseline: 1.1162x; 1.1162x over previous
//
#include <hip/hip_runtime.h>
#include <math.h>

#define NPTS 32768
#define NB 32
#define PP 1024
#define KK 20

using bf16x8 = __attribute__((ext_vector_type(8))) short;
using f32x4 = __attribute__((ext_vector_type(4))) float;

// ---------------- workspace layout ----------------
constexpr size_t OFF_X1 = 0;                                  // x1hl [N,128] bf16 (hi 0..63, lo 64..127)
constexpr size_t OFF_IDX = OFF_X1 + (size_t)NPTS * 64 * 4;    // [N,20] i32
constexpr size_t OFF_U = OFF_IDX + (size_t)NPTS * KK * 4;     // u2 [N,128] f32
constexpr size_t OFF_V = OFF_U + (size_t)NPTS * 128 * 4;      // v2 [N,128] f32
constexpr size_t OFF_X2 = OFF_V + (size_t)NPTS * 128 * 4;     // x2hl [N,256] bf16
constexpr size_t OFF_H = OFF_X2 + (size_t)NPTS * 128 * 4;     // part (lin partial maxes)
constexpr size_t OFF_PART = OFF_H + (size_t)NPTS * 128 * 4;   // (unused)
constexpr size_t OFF_SQN = OFF_PART + (size_t)32 * 8 * 128 * 4;  // [N] f32
// pk (both kNNs) @ OFF_U: N*8*20 u32 = 21 MB, spans U + start of V.
//  knn1 pk dead before precompute1 writes u1/v1.
//  knn2 pk written after edge_conv1 consumed u1/v1, dead before pre2_mfma.

// ---------------- register top-K: v_med3_u32 insert ----------------
__device__ __forceinline__ void topk_insert(unsigned (&l)[KK], unsigned key) {
#pragma unroll
  for (int j = KK - 1; j >= 1; --j) {
    unsigned r;
    asm("v_med3_u32 %0, %1, %2, %3" : "=v"(r) : "v"(key), "v"(l[j - 1]), "v"(l[j]));
    l[j] = r;
  }
  l[0] = key < l[0] ? key : l[0];
}

__device__ __forceinline__ unsigned pack_key(float dist, int q) {
  return (__float_as_uint(dist) & 0xFFFFFC00u) | (unsigned)q;
}

// hi/lo bf16 split: |x - (hi+lo)| <= 2^-16 |x|
__device__ __forceinline__ void split_bf16(float x, short& hi, short& lo) {
  unsigned u = __float_as_uint(x);
  hi = (short)(u >> 16);
  float fh = __uint_as_float(u & 0xFFFF0000u);
  float r = x - fh;
  lo = (short)(__float_as_uint(r) >> 16);
}

// ---------------- kNN1 (D=3): LDS SoA, dual lists merged in-kernel ----------------
template <int S>
__global__ __launch_bounds__(256, 4) void knn_topk3(const float* __restrict__ x,
                                                    unsigned* __restrict__ pk) {
  constexpr int CH = PP / S;
  __shared__ __align__(16) float xs[1024];
  __shared__ __align__(16) float ys[1024];
  __shared__ __align__(16) float zs[1024];
  int bx = blockIdx.x;
  int s = bx % S;
  int tile = (bx / S) % (PP / 256);
  int b = bx / (S * (PP / 256));
  int tid = threadIdx.x;
  const float* xb = x + (size_t)b * PP * 3;

  for (int t = tid; t < 768; t += 256) {
    float4 v = ((const float4*)xb)[t];
    int e = 4 * t;
    float vals[4] = {v.x, v.y, v.z, v.w};
#pragma unroll
    for (int j = 0; j < 4; ++j) {
      int p = (e + j) / 3, d = (e + j) % 3;
      if (d == 0) xs[p] = vals[j];
      else if (d == 1) ys[p] = vals[j];
      else zs[p] = vals[j];
    }
  }
  __syncthreads();

  int i = tile * 256 + tid;
  float xi0 = xs[i], xi1 = ys[i], xi2 = zs[i];

  unsigned la[KK], lb_[KK];
#pragma unroll
  for (int j = 0; j < KK; ++j) { la[j] = 0xFFFFFFFFu; lb_[j] = 0xFFFFFFFFu; }

  int q0 = s * CH;
  float4 qx = *(const float4*)&xs[q0];
  float4 qy = *(const float4*)&ys[q0];
  float4 qz = *(const float4*)&zs[q0];
  for (int c = 0; c < CH; c += 4) {
    int qm = (q0 + c + 4) & 1023;  // masked: last prefetch unused
    float4 nqx = *(const float4*)&xs[qm];
    float4 nqy = *(const float4*)&ys[qm];
    float4 nqz = *(const float4*)&zs[qm];
    float cx[4] = {qx.x, qx.y, qx.z, qx.w};
    float cy[4] = {qy.x, qy.y, qy.z, qy.w};
    float cz[4] = {qz.x, qz.y, qz.z, qz.w};
    {
      float d0 = xi0 - cx[0], d1 = xi1 - cy[0], d2 = xi2 - cz[0];
      float e0 = xi0 - cx[2], e1 = xi1 - cy[2], e2 = xi2 - cz[2];
      topk_insert(la, pack_key(fmaf(d0, d0, fmaf(d1, d1, d2 * d2)), q0 + c + 0));
      topk_insert(lb_, pack_key(fmaf(e0, e0, fmaf(e1, e1, e2 * e2)), q0 + c + 2));
    }
    {
      float d0 = xi0 - cx[1], d1 = xi1 - cy[1], d2 = xi2 - cz[1];
      float e0 = xi0 - cx[3], e1 = xi1 - cy[3], e2 = xi2 - cz[3];
      topk_insert(la, pack_key(fmaf(d0, d0, fmaf(d1, d1, d2 * d2)), q0 + c + 1));
      topk_insert(lb_, pack_key(fmaf(e0, e0, fmaf(e1, e1, e2 * e2)), q0 + c + 3));
    }
    qx = nqx; qy = nqy; qz = nqz;
  }
  for (int j = 0; j < KK; ++j) {
    unsigned key = lb_[j];
    if (key >= la[KK - 1]) break;
    topk_insert(la, key);
  }
  size_t base = ((size_t)b * PP + i) * S + s;
#pragma unroll
  for (int j = 0; j < KK; ++j) pk[base * KK + j] = la[j];
}

// merge S sorted sublists; early break exact (keys unique, ascending)
template <int S>
__global__ __launch_bounds__(256) void knn_merge(const unsigned* __restrict__ pk,
                                                 int* __restrict__ idx_out) {
  int p = blockIdx.x * 256 + threadIdx.x;
  const unsigned* g = pk + (size_t)p * S * KK;
  unsigned l[KK];
#pragma unroll
  for (int j = 0; j < KK; ++j) l[j] = g[j];
  for (int s = 1; s < S; ++s) {
    const unsigned* gs = g + s * KK;
    for (int j = 0; j < KK; ++j) {
      unsigned key = gs[j];
      if (key >= l[KK - 1]) break;  // sorted: rest cannot qualify
      topk_insert(l, key);
    }
  }
#pragma unroll
  for (int j = 0; j < KK; ++j) idx_out[(size_t)p * KK + j] = (int)(l[j] & 1023u);
}

// ---------------- EdgeConv1 precompute ----------------
__global__ __launch_bounds__(256) void precompute1(const float* __restrict__ pos,
                                                   const float* __restrict__ W1,
                                                   const float* __restrict__ b1,
                                                   float* __restrict__ u1,
                                                   float* __restrict__ v1) {
  int gid = blockIdx.x * 256 + threadIdx.x;  // over N*64
  int i = gid >> 6, c = gid & 63;
  float p0 = pos[(size_t)i * 3 + 0], p1 = pos[(size_t)i * 3 + 1], p2 = pos[(size_t)i * 3 + 2];
  float a0 = W1[0 * 64 + c], a1 = W1[1 * 64 + c], a2 = W1[2 * 64 + c];
  float g0 = W1[3 * 64 + c], g1 = W1[4 * 64 + c], g2 = W1[5 * 64 + c];
  float v = fmaf(p0, g0, fmaf(p1, g1, p2 * g2));
  float u = b1[c];
  u = fmaf(p0, a0 - g0, u);
  u = fmaf(p1, a1 - g1, u);
  u = fmaf(p2, a2 - g2, u);
  u1[gid] = u;
  v1[gid] = v;
}

// ---------------- EdgeConv1 via MFMA: k-outer, max in registers (R11 form) ----------------
__global__ __launch_bounds__(256) void edge_conv1_mfma(
    const float* __restrict__ u1, const float* __restrict__ v1,
    const int* __restrict__ idx, const float* __restrict__ W2,
    const float* __restrict__ scale, const float* __restrict__ bias,
    const float* __restrict__ b2,
    short* __restrict__ x1hl, float* __restrict__ sqn) {
  __shared__ int jt[32 * KK];
  __shared__ float mxs[32 * 68];
  int tid = threadIdx.x;
  int p0 = blockIdx.x * 32;  // 32 | 1024: no cloud straddle
  int b = p0 >> 10;
  for (int t = tid; t < 32 * KK; t += 256)
    jt[t] = (b << 10) + idx[(size_t)(p0 + t / KK) * KK + t % KK];
  int w = tid >> 6, l = tid & 63, quad = l >> 4, lm = l & 15;
  int group = w >> 1, khalf = w & 1;
  int kq = quad * 8;
  bf16x8 Bh[4][2], Bl[4][2];
#pragma unroll
  for (int nt = 0; nt < 4; ++nt) {
#pragma unroll
    for (int ks = 0; ks < 2; ++ks) {
#pragma unroll
      for (int jj = 0; jj < 8; ++jj) {
        float wv = W2[(size_t)(ks * 32 + kq + jj) * 64 + nt * 16 + lm];
        short hi, lo;
        split_bf16(wv, hi, lo);
        Bh[nt][ks][jj] = hi;
        Bl[nt][ks][jj] = lo;
      }
    }
  }
  int myp = group * 16 + lm;  // local point 0..31
  const float* urow = u1 + (size_t)(p0 + myp) * 64;
  float up[2][8], sc[2][8];
#pragma unroll
  for (int ks = 0; ks < 2; ++ks) {
    int koff = ks * 32 + kq;
    float4 ua = *(const float4*)(urow + koff);
    float4 ub = *(const float4*)(urow + koff + 4);
    float4 sa = *(const float4*)(scale + koff);
    float4 sb = *(const float4*)(scale + koff + 4);
    float4 ca = *(const float4*)(bias + koff);
    float4 cb4 = *(const float4*)(bias + koff + 4);
    sc[ks][0] = sa.x; sc[ks][1] = sa.y; sc[ks][2] = sa.z; sc[ks][3] = sa.w;
    sc[ks][4] = sb.x; sc[ks][5] = sb.y; sc[ks][6] = sb.z; sc[ks][7] = sb.w;
    up[ks][0] = fmaf(ua.x, sa.x, ca.x);
    up[ks][1] = fmaf(ua.y, sa.y, ca.y);
    up[ks][2] = fmaf(ua.z, sa.z, ca.z);
    up[ks][3] = fmaf(ua.w, sa.w, ca.w);
    up[ks][4] = fmaf(ub.x, sb.x, cb4.x);
    up[ks][5] = fmaf(ub.y, sb.y, cb4.y);
    up[ks][6] = fmaf(ub.z, sb.z, cb4.z);
    up[ks][7] = fmaf(ub.w, sb.w, cb4.w);
  }
  float b2v[4];
#pragma unroll
  for (int nt = 0; nt < 4; ++nt) b2v[nt] = b2[nt * 16 + lm];
  __syncthreads();

  f32x4 mx[4];
#pragma unroll
  for (int nt = 0; nt < 4; ++nt)
    mx[nt] = (f32x4){-__builtin_inff(), -__builtin_inff(), -__builtin_inff(), -__builtin_inff()};

  for (int k = khalf * 10; k < khalf * 10 + 10; ++k) {
    int j = jt[myp * KK + k];
    const float* vrow = v1 + (size_t)j * 64;
    f32x4 acc[4];
#pragma unroll
    for (int nt = 0; nt < 4; ++nt) acc[nt] = (f32x4){0.f, 0.f, 0.f, 0.f};
#pragma unroll
    for (int ks = 0; ks < 2; ++ks) {
      int koff = ks * 32 + kq;
      float4 va = *(const float4*)(vrow + koff);
      float4 vb = *(const float4*)(vrow + koff + 4);
      float hv[8];
      hv[0] = fmaxf(fmaf(va.x, sc[ks][0], up[ks][0]), 0.f);
      hv[1] = fmaxf(fmaf(va.y, sc[ks][1], up[ks][1]), 0.f);
      hv[2] = fmaxf(fmaf(va.z, sc[ks][2], up[ks][2]), 0.f);
      hv[3] = fmaxf(fmaf(va.w, sc[ks][3], up[ks][3]), 0.f);
      hv[4] = fmaxf(fmaf(vb.x, sc[ks][4], up[ks][4]), 0.f);
      hv[5] = fmaxf(fmaf(vb.y, sc[ks][5], up[ks][5]), 0.f);
      hv[6] = fmaxf(fmaf(vb.z, sc[ks][6], up[ks][6]), 0.f);
      hv[7] = fmaxf(fmaf(vb.w, sc[ks][7], up[ks][7]), 0.f);
      bf16x8 Ah, Al;
#pragma unroll
      for (int jj = 0; jj < 8; ++jj) {
        short hi, lo;
        split_bf16(hv[jj], hi, lo);
        Ah[jj] = hi;
        Al[jj] = lo;
      }
#pragma unroll
      for (int nt = 0; nt < 4; ++nt) {
        acc[nt] = __builtin_amdgcn_mfma_f32_16x16x32_bf16(Ah, Bh[nt][ks], acc[nt], 0, 0, 0);
        acc[nt] = __builtin_amdgcn_mfma_f32_16x16x32_bf16(Al, Bh[nt][ks], acc[nt], 0, 0, 0);
        acc[nt] = __builtin_amdgcn_mfma_f32_16x16x32_bf16(Ah, Bl[nt][ks], acc[nt], 0, 0, 0);
      }
    }
#pragma unroll
    for (int nt = 0; nt < 4; ++nt) {
#pragma unroll
      for (int r = 0; r < 4; ++r) mx[nt][r] = fmaxf(mx[nt][r], acc[nt][r]);
    }
  }
  if (khalf == 1) {
#pragma unroll
    for (int nt = 0; nt < 4; ++nt)
#pragma unroll
      for (int r = 0; r < 4; ++r)
        mxs[(group * 16 + quad * 4 + r) * 68 + nt * 16 + lm] = mx[nt][r];
  }
  __syncthreads();
  if (khalf == 0) {
#pragma unroll
    for (int nt = 0; nt < 4; ++nt) {
#pragma unroll
      for (int r = 0; r < 4; ++r) {
        int p = group * 16 + quad * 4 + r;
        int c = nt * 16 + lm;
        float m = fmaxf(mx[nt][r], mxs[p * 68 + c]) + b2v[nt];
        short hi, lo;
        split_bf16(m, hi, lo);
        size_t gi = (size_t)(p0 + p) * 128 + c;
        x1hl[gi] = hi;
        x1hl[gi + 64] = lo;
        mxs[p * 68 + c] = m;  // disjoint (p,c) per thread: no race
      }
    }
  }
  __syncthreads();
  if (tid < 32) {
    float ss = 0.f;
    for (int c = 0; c < 64; ++c) {
      float v = mxs[tid * 68 + c];
      ss = fmaf(v, v, ss);
    }
    sqn[p0 + tid] = ss;
  }
}

// ---------------- kNN2 via MFMA: double-buffered LDS tiles + dual lists ----------------
__global__ __launch_bounds__(256, 4) void knn2_mfma(const short* __restrict__ x1hl,
                                                    const float* __restrict__ sqn,
                                                    unsigned* __restrict__ pk) {
  constexpr int TS = 72;
  __shared__ float sqs[512];
  __shared__ __align__(16) short tileH[2][64 * TS];
  __shared__ __align__(16) short tileL[2][64 * TS];
  int bx = blockIdx.x;
  int s = bx & 1;
  int pb = bx >> 1;
  int p0 = pb * 64;
  int b = p0 >> 10;
  int tid = threadIdx.x;
  for (int t = tid; t < 512; t += 256) sqs[t] = sqn[(size_t)b * PP + s * 512 + t];
  int w = tid >> 6, l = tid & 63, quad = l >> 4, lm = l & 15;
  size_t gi = (size_t)p0 + w * 16 + lm;
  const short* brow = x1hl + gi * 128 + quad * 8;
  bf16x8 Bh0 = *(const bf16x8*)(brow);
  bf16x8 Bl0 = *(const bf16x8*)(brow + 64);
  bf16x8 Bh1 = *(const bf16x8*)(brow + 32);
  bf16x8 Bl1 = *(const bf16x8*)(brow + 96);
  float sqi = sqn[gi];

  unsigned la[KK], lc[KK];
#pragma unroll
  for (int j = 0; j < KK; ++j) { la[j] = 0xFFFFFFFFu; lc[j] = 0xFFFFFFFFu; }

  int rr = tid & 63, seg = tid >> 6;
  const short* srcbase = x1hl + ((size_t)b * PP + s * 512 + rr) * 128 + seg * 32;
  {
    bf16x8 r0 = *(const bf16x8*)(srcbase);
    bf16x8 r1 = *(const bf16x8*)(srcbase + 8);
    bf16x8 r2 = *(const bf16x8*)(srcbase + 16);
    bf16x8 r3 = *(const bf16x8*)(srcbase + 24);
    short* dst = ((seg < 2) ? tileH[0] : tileL[0]) + rr * TS + (seg & 1) * 32;
    *(bf16x8*)(dst) = r0;
    *(bf16x8*)(dst + 8) = r1;
    *(bf16x8*)(dst + 16) = r2;
    *(bf16x8*)(dst + 24) = r3;
  }
  __syncthreads();

  for (int tile = 0; tile < 8; ++tile) {
    int buf = tile & 1;
    bf16x8 r0, r1, r2, r3;
    if (tile < 7) {
      const short* src = srcbase + (size_t)(tile + 1) * 64 * 128;
      r0 = *(const bf16x8*)(src);
      r1 = *(const bf16x8*)(src + 8);
      r2 = *(const bf16x8*)(src + 16);
      r3 = *(const bf16x8*)(src + 24);
    }
#pragma unroll
    for (int it = 0; it < 4; ++it) {
      int row = it * 16 + lm;
      const short* aH = tileH[buf] + row * TS + quad * 8;
      const short* aL = tileL[buf] + row * TS + quad * 8;
      bf16x8 Ah0 = *(const bf16x8*)(aH);
      bf16x8 Ah1 = *(const bf16x8*)(aH + 32);
      bf16x8 Al0 = *(const bf16x8*)(aL);
      bf16x8 Al1 = *(const bf16x8*)(aL + 32);

      f32x4 acc = (f32x4){0.f, 0.f, 0.f, 0.f};
      acc = __builtin_amdgcn_mfma_f32_16x16x32_bf16(Ah0, Bh0, acc, 0, 0, 0);
      acc = __builtin_amdgcn_mfma_f32_16x16x32_bf16(Al0, Bh0, acc, 0, 0, 0);
      acc = __builtin_amdgcn_mfma_f32_16x16x32_bf16(Ah0, Bl0, acc, 0, 0, 0);
      acc = __builtin_amdgcn_mfma_f32_16x16x32_bf16(Ah1, Bh1, acc, 0, 0, 0);
      acc = __builtin_amdgcn_mfma_f32_16x16x32_bf16(Al1, Bh1, acc, 0, 0, 0);
      acc = __builtin_amdgcn_mfma_f32_16x16x32_bf16(Ah1, Bl1, acc, 0, 0, 0);

      int qloc = tile * 64 + it * 16 + quad * 4;
      int qg = s * 512 + qloc;
      float d0 = fmaxf(0.f, fmaf(-2.f, acc[0], sqi + sqs[qloc + 0]));
      float d2 = fmaxf(0.f, fmaf(-2.f, acc[2], sqi + sqs[qloc + 2]));
      topk_insert(la, pack_key(d0, qg + 0));
      topk_insert(lc, pack_key(d2, qg + 2));
      float d1 = fmaxf(0.f, fmaf(-2.f, acc[1], sqi + sqs[qloc + 1]));
      float d3 = fmaxf(0.f, fmaf(-2.f, acc[3], sqi + sqs[qloc + 3]));
      topk_insert(la, pack_key(d1, qg + 1));
      topk_insert(lc, pack_key(d3, qg + 3));
    }
    if (tile < 7) {
      __syncthreads();
      short* dst = ((seg < 2) ? tileH[buf ^ 1] : tileL[buf ^ 1]) + rr * TS + (seg & 1) * 32;
      *(bf16x8*)(dst) = r0;
      *(bf16x8*)(dst + 8) = r1;
      *(bf16x8*)(dst + 16) = r2;
      *(bf16x8*)(dst + 24) = r3;
      __syncthreads();
    }
  }
  for (int j = 0; j < KK; ++j) {
    unsigned key = lc[j];
    if (key >= la[KK - 1]) break;
    topk_insert(la, key);
  }
  unsigned sub = (unsigned)(s * 4 + quad);
  unsigned* dst = pk + ((size_t)gi * 8 + sub) * KK;
#pragma unroll
  for (int j = 0; j < KK; ++j) dst[j] = la[j];
}

// ---------------- EdgeConv2 precompute via MFMA ----------------
__global__ __launch_bounds__(256) void pre2_mfma(const short* __restrict__ x1hl,
                                                 const float* __restrict__ cW,
                                                 const float* __restrict__ cb,
                                                 float* __restrict__ u2,
                                                 float* __restrict__ v2) {
  constexpr int BS = 72;
  __shared__ short Bh[128 * BS];
  __shared__ short Bl[128 * BS];
  int tid = threadIdx.x;
  int nh = blockIdx.x & 1;
  int p0 = (blockIdx.x >> 1) * 64;
  for (int t = tid; t < 64 * 128; t += 256) {
    int k = t >> 7, n = t & 127;
    float wb_ = cW[(size_t)(64 + k) * 128 + n];
    float wv = nh ? wb_ : (cW[(size_t)k * 128 + n] - wb_);
    short hi, lo;
    split_bf16(wv, hi, lo);
    Bh[n * BS + k] = hi;
    Bl[n * BS + k] = lo;
  }
  __syncthreads();
  int w = tid >> 6, l = tid & 63, quad = l >> 4, lm = l & 15;
  int row = p0 + w * 16 + lm;
  f32x4 acc[8];
#pragma unroll
  for (int nt = 0; nt < 8; ++nt) acc[nt] = (f32x4){0.f, 0.f, 0.f, 0.f};
#pragma unroll
  for (int ks = 0; ks < 2; ++ks) {
    int kb = ks * 32 + quad * 8;
    bf16x8 Ah = *(const bf16x8*)(x1hl + (size_t)row * 128 + kb);
    bf16x8 Al = *(const bf16x8*)(x1hl + (size_t)row * 128 + 64 + kb);
#pragma unroll
    for (int nt = 0; nt < 8; ++nt) {
      bf16x8 Wh = *(const bf16x8*)(Bh + (nt * 16 + lm) * BS + kb);
      bf16x8 Wl = *(const bf16x8*)(Bl + (nt * 16 + lm) * BS + kb);
      acc[nt] = __builtin_amdgcn_mfma_f32_16x16x32_bf16(Ah, Wh, acc[nt], 0, 0, 0);
      acc[nt] = __builtin_amdgcn_mfma_f32_16x16x32_bf16(Al, Wh, acc[nt], 0, 0, 0);
      acc[nt] = __builtin_amdgcn_mfma_f32_16x16x32_bf16(Ah, Wl, acc[nt], 0, 0, 0);
    }
  }
  float* out = nh ? v2 : u2;
  int prow = p0 + w * 16 + quad * 4;
#pragma unroll
  for (int nt = 0; nt < 8; ++nt) {
    int col = nt * 16 + lm;
    float bias = nh ? 0.f : cb[col];
#pragma unroll
    for (int r = 0; r < 4; ++r)
      out[(size_t)(prow + r) * 128 + col] = acc[nt][r] + bias;
  }
}

__global__ __launch_bounds__(256) void gathermax2(const float* __restrict__ u2,
                                                  const float* __restrict__ v2,
                                                  const int* __restrict__ idx,
                                                  short* __restrict__ x2hl) {
  int gid = blockIdx.x * 256 + threadIdx.x;  // over N*128
  int i = gid >> 7, c = gid & 127;
  int b = i >> 10;
  const int* myidx = idx + (size_t)i * KK;
  float m = -__builtin_inff();
  for (int k = 0; k < KK; ++k) {
    int j = (b << 10) + myidx[k];
    m = fmaxf(m, v2[(size_t)j * 128 + c]);
  }
  float x = u2[gid] + m;
  short hi, lo;
  split_bf16(x, hi, lo);
  x2hl[(size_t)i * 256 + c] = hi;
  x2hl[(size_t)i * 256 + 128 + c] = lo;
}

// ---------------- final linear via MFMA, fused per-block segment-max ----------------
// Writes only per-(cloud,chunk,nh) partial maxes; h never materialized.
__global__ __launch_bounds__(256) void lin_mfma(const short* __restrict__ x1hl,
                                                const short* __restrict__ x2hl,
                                                const float* __restrict__ LW,
                                                const float* __restrict__ lb,
                                                float* __restrict__ part) {
  constexpr int BS = 200;
  __shared__ short Bh[64 * BS];
  __shared__ short Bl[64 * BS];
  __shared__ float red[16][68];
  int tid = threadIdx.x;
  int nh = blockIdx.x & 1;
  int p0 = (blockIdx.x >> 1) * 64;
  for (int t = tid; t < 192 * 64; t += 256) {
    int k = t >> 6, n = t & 63;
    float wv = LW[(size_t)k * 128 + nh * 64 + n];
    short hi, lo;
    split_bf16(wv, hi, lo);
    Bh[n * BS + k] = hi;
    Bl[n * BS + k] = lo;
  }
  __syncthreads();
  int w = tid >> 6, l = tid & 63, quad = l >> 4, lm = l & 15;
  int row = p0 + w * 16 + lm;
  f32x4 acc[4];
#pragma unroll
  for (int nt = 0; nt < 4; ++nt) acc[nt] = (f32x4){0.f, 0.f, 0.f, 0.f};
#pragma unroll
  for (int ks = 0; ks < 6; ++ks) {
    int kb = ks * 32 + quad * 8;
    bf16x8 Ah, Al;
    if (ks < 2) {
      Ah = *(const bf16x8*)(x1hl + (size_t)row * 128 + kb);
      Al = *(const bf16x8*)(x1hl + (size_t)row * 128 + 64 + kb);
    } else {
      Ah = *(const bf16x8*)(x2hl + (size_t)row * 256 + (kb - 64));
      Al = *(const bf16x8*)(x2hl + (size_t)row * 256 + 128 + (kb - 64));
    }
#pragma unroll
    for (int nt = 0; nt < 4; ++nt) {
      bf16x8 Wh = *(const bf16x8*)(Bh + (nt * 16 + lm) * BS + kb);
      bf16x8 Wl = *(const bf16x8*)(Bl + (nt * 16 + lm) * BS + kb);
      acc[nt] = __builtin_amdgcn_mfma_f32_16x16x32_bf16(Ah, Wh, acc[nt], 0, 0, 0);
      acc[nt] = __builtin_amdgcn_mfma_f32_16x16x32_bf16(Al, Wh, acc[nt], 0, 0, 0);
      acc[nt] = __builtin_amdgcn_mfma_f32_16x16x32_bf16(Ah, Wl, acc[nt], 0, 0, 0);
    }
  }
  // fused epilogue: max over this thread's 4 rows (+col bias — exact commute),
  // then 16-group LDS max reduce over the block's 64 points.
  int g = w * 4 + quad;
#pragma unroll
  for (int nt = 0; nt < 4; ++nt) {
    int col = nh * 64 + nt * 16 + lm;
    float m = fmaxf(fmaxf(acc[nt][0], acc[nt][1]), fmaxf(acc[nt][2], acc[nt][3])) + lb[col];
    red[g][nt * 16 + lm] = m;
  }
  __syncthreads();
  if (tid < 64) {
    float m = red[0][tid];
#pragma unroll
    for (int gg = 1; gg < 16; ++gg) m = fmaxf(m, red[gg][tid]);
    int b = p0 >> 10, chunk = (p0 >> 6) & 15;
    part[(((size_t)b * 16 + chunk) * 2 + nh) * 64 + tid] = m;
  }
}

__global__ __launch_bounds__(128) void segmax_b(const float* __restrict__ part,
                                                float* __restrict__ out) {
  int b = blockIdx.x;
  int c0 = threadIdx.x;  // 0..127: nh*64 + local col
  int nh = c0 >> 6, c = c0 & 63;
  float m = -__builtin_inff();
  for (int ch = 0; ch < 16; ++ch)
    m = fmaxf(m, part[(((size_t)b * 16 + ch) * 2 + nh) * 64 + c]);
  out[(size_t)b * 128 + c0] = m;
}

// ---------------- launch ----------------
extern "C" void kernel_launch(void* const* d_in, const int* in_sizes, int n_in,
                              void* d_out, int out_size, void* d_ws, size_t ws_size,
                              hipStream_t stream) {
  const float* pos = (const float*)d_in[0];
  const float* W1 = (const float*)d_in[2];
  const float* b1 = (const float*)d_in[3];
  const float* bn_s = (const float*)d_in[4];
  const float* bn_b = (const float*)d_in[5];
  const float* W2 = (const float*)d_in[6];
  const float* b2 = (const float*)d_in[7];
  const float* cW = (const float*)d_in[8];
  const float* cb = (const float*)d_in[9];
  const float* LW = (const float*)d_in[10];
  const float* lb = (const float*)d_in[11];
  float* out = (float*)d_out;

  char* ws = (char*)d_ws;
  short* x1hl = (short*)(ws + OFF_X1);
  int* idx = (int*)(ws + OFF_IDX);
  float* u1 = (float*)(ws + OFF_U);
  float* v1 = (float*)(ws + OFF_V);
  float* u2 = (float*)(ws + OFF_U);
  float* v2 = (float*)(ws + OFF_V);
  short* x2hl = (short*)(ws + OFF_X2);
  float* part = (float*)(ws + OFF_H);  // reuses dead h region
  float* sqn = (float*)(ws + OFF_SQN);
  unsigned* pk = (unsigned*)(ws + OFF_U);  // see lifetime notes above

  // 1. kNN on pos (8-way split, dual lists merged in-kernel -> 8 sublists)
  knn_topk3<8><<<NB * 4 * 8, 256, 0, stream>>>(pos, pk);
  knn_merge<8><<<NPTS / 256, 256, 0, stream>>>(pk, idx);
  // 2. u1/v1
  precompute1<<<NPTS * 64 / 256, 256, 0, stream>>>(pos, W1, b1, u1, v1);
  // 3. EdgeConv1 (MFMA, R11 k-halved reg-max) -> x1hl + sqn
  edge_conv1_mfma<<<NPTS / 32, 256, 0, stream>>>(u1, v1, idx, W2, bn_s, bn_b, b2,
                                                 x1hl, sqn);
  // 4. kNN on x1 (MFMA + double-buffered LDS tiles, in-kernel dual-list merge)
  knn2_mfma<<<NPTS / 64 * 2, 256, 0, stream>>>(x1hl, sqn, pk);
  knn_merge<8><<<NPTS / 256, 256, 0, stream>>>(pk, idx);
  // 5. u2/v2 (MFMA)
  pre2_mfma<<<NPTS / 64 * 2, 256, 0, stream>>>(x1hl, cW, cb, u2, v2);
  // 6. gather + max -> x2hl
  gathermax2<<<NPTS * 128 / 256, 256, 0, stream>>>(u2, v2, idx, x2hl);
  // 7. final linear (MFMA) + fused per-block segmax -> part
  lin_mfma<<<NPTS / 64 * 2, 256, 0, stream>>>(x1hl, x2hl, LW, lb, part);
  // 8. final reduce -> out
  segmax_b<<<NB, 128, 0, stream>>>(part, out);
}